// Round 5
// baseline (283.945 us; speedup 1.0000x reference)
//
#include <hip/hip_runtime.h>
#include <hip/hip_bf16.h>

// B=1024, D_IN=64, H=128, D_OUT=16
// inputs:  fp32  x[1024,64] W1[64,128] b1[128] W2[128,16] b2[16]
// outputs: fp32, flat: f[1024*16] | df[1024*64*16] | d2f[1024*64*64*16]
//
// Math per sample: z = x@W1+b1, a=tanh(z), s=1-a^2, t=-2*a*s
//   f          = a@W2 + b2
//   df[i,j]    = sum_h W1[i,h] s_h W2[h,j]          (exact f32)
//   d2f[k,i,j] = sum_h W1[i,h] W1[k,h] t_h W2[h,j]  (bf16 MFMA, f32 acc)
//
// SINGLE fused kernel, grid (128,4) x 256thr = 512 blocks (2/CU). Block (bg, mb):
//   - d2f for samples b0..b0+7 (b0 = bg*8), row-quarter mb (1024 of 4096 U-rows)
//   - f/df for sample pair {b0+2mb, b0+2mb+1}
// 8 samples/block doubles MFMA work per A-fragment synthesis (the per-mt
// 16x ds_read_b128 + mul/cvt now feeds 32 MFMAs instead of 16), halving
// the non-store overhead per byte of output. Stores stay cached (R4 A/B won).

typedef unsigned short u16;
typedef short s8v __attribute__((ext_vector_type(8)));   // 8 bf16 = 4 VGPRs (A/B frag)
typedef float f4v __attribute__((ext_vector_type(4)));

__device__ __forceinline__ u16 f2bf(float f){
  __hip_bfloat16 h = __float2bfloat16(f);   // RNE
  return __builtin_bit_cast(u16, h);
}

#define W1S 132   // padded LDS stride for W1 rows

__global__ __launch_bounds__(256, 2) void k_all(
    const float* __restrict__ x, const float* __restrict__ W1, const float* __restrict__ b1,
    const float* __restrict__ W2, const float* __restrict__ b2,
    float* __restrict__ f_out, float* __restrict__ df_out, float* __restrict__ d2f)
{
  const int tid  = threadIdx.x;
  const int lane = tid & 63;
  const int wave = tid >> 6;
  const int n = lane & 15;      // MFMA position
  const int q = lane >> 4;      // quad (K-block)
  const int b0 = blockIdx.x * 8;
  const int mb = blockIdx.y;    // 0..3: d2f row-quarter AND f/df sample-pair selector

  __shared__ float sW1[64 * W1S];            // f32 W1, padded rows (33.8 KB)
  __shared__ __align__(16) float sGF[8192];  // phase A: bf16 G x8 swizzled (32 KB); phase B head: f32 s*W2 (16 KB)
  __shared__ float sx[512];                  // phase A: x for 8 samples; phase B: a for 2 samples
  u16* sG = (u16*)sGF;

  // ---- stage W1 (8192 floats) and x (512 floats) ----
#pragma unroll
  for (int v = 0; v < 8; ++v){
    int idx = v*256 + tid;              // float4 index
    int r = idx >> 5;
    int c = (idx & 31) << 2;
    *(f4v*)&sW1[r*W1S + c] = *(const f4v*)&W1[r*128 + c];
  }
#pragma unroll
  for (int v = 0; v < 2; ++v)
    sx[v*256 + tid] = x[b0*64 + v*256 + tid];
  __syncthreads();

  // ---- z-pass: all 8 samples -> sG (bf16, XOR-swizzled). Keep a,s of it==mb in regs ----
  float a_keep = 0.f, s_keep = 0.f;
#pragma unroll
  for (int it = 0; it < 4; ++it){
    int idx = it*256 + tid;             // (s,h) item, 1024 total
    int s = idx >> 7;                   // = it*2 + (tid>>7)
    int h = idx & 127;
    float z = b1[h];
#pragma unroll 8
    for (int i = 0; i < 64; ++i) z += sx[s*64 + i] * sW1[i*W1S + h];
    float a = tanhf(z);
    float sd = 1.0f - a*a;              // tanh'
    float t = -2.0f * a * sd;           // tanh''
    if (it == mb){ a_keep = a; s_keep = sd; }
    f4v w2r[4];
#pragma unroll
    for (int v2 = 0; v2 < 4; ++v2) w2r[v2] = *(const f4v*)&W2[h*16 + v2*4];
#pragma unroll
    for (int j = 0; j < 16; ++j){
      int byte = (j*256 + h*2) ^ ((j & 7) << 4);   // bank-spread swizzle
      sG[s*2048 + (byte >> 1)] = f2bf(t * w2r[j >> 2][j & 3]);
    }
  }
  __syncthreads();

  // ---- B-fragments (G^T): lane(n,q), ks -> G[s][j=n][h=q*8+ks*32+e], s=0..7 ----
  s8v bfrag[8][4];
#pragma unroll
  for (int s = 0; s < 8; ++s){
#pragma unroll
    for (int ks = 0; ks < 4; ++ks){
      int byte = (n*256 + q*16 + ks*64) ^ ((n & 7) << 4);
      bfrag[s][ks] = *(const s8v*)&sG[s*2048 + (byte >> 1)];
    }
  }
  __syncthreads();   // all sG reads complete -> safe to repurpose sGF/sx

  // ---- phase B: f and df for samples {b0+2mb, b0+2mb+1} (exact f32, mirrors old k1) ----
  {
    const int ls = tid >> 7;            // 0/1 = local sample
    const int h  = tid & 127;
    float* sF = sGF;                    // [2][128][16] f32 s*W2 (16 KB head of sGF)
    sx[tid] = a_keep;                   // sx[ls*128+h] == a of sample b0+2mb+ls
    f4v w2r[4];
#pragma unroll
    for (int v2 = 0; v2 < 4; ++v2) w2r[v2] = *(const f4v*)&W2[h*16 + v2*4];
#pragma unroll
    for (int v2 = 0; v2 < 4; ++v2){
      f4v sv;
#pragma unroll
      for (int e = 0; e < 4; ++e) sv[e] = s_keep * w2r[v2][e];
      *(f4v*)&sF[ls*2048 + h*16 + v2*4] = sv;
    }
    __syncthreads();

    const int sub = tid & 127;
    const int i   = sub >> 1;
    const int j0  = (sub & 1) * 8;
    const int bS  = b0 + 2*mb + ls;
    float acc[8] = {0,0,0,0,0,0,0,0};
    for (int h0 = 0; h0 < 128; h0 += 8){
      const float4* wp = (const float4*)&W1[i*128 + h0];   // global, L1-hot, exact k1 order
      float4 wa = wp[0], wb = wp[1];
      float wf[8] = {wa.x, wa.y, wa.z, wa.w, wb.x, wb.y, wb.z, wb.w};
#pragma unroll
      for (int hh = 0; hh < 8; ++hh){
        const f4v* sp = (const f4v*)&sF[ls*2048 + (h0 + hh)*16 + j0];
        f4v A = sp[0], Bv = sp[1];
        float w1 = wf[hh];
        acc[0] += w1*A[0];  acc[1] += w1*A[1];  acc[2] += w1*A[2];  acc[3] += w1*A[3];
        acc[4] += w1*Bv[0]; acc[5] += w1*Bv[1]; acc[6] += w1*Bv[2]; acc[7] += w1*Bv[3];
      }
    }
    f4v v0 = {acc[0], acc[1], acc[2], acc[3]};
    f4v v1 = {acc[4], acc[5], acc[6], acc[7]};
    float* dp = &df_out[bS*1024 + i*16 + j0];
    __builtin_nontemporal_store(v0, (f4v*)dp);
    __builtin_nontemporal_store(v1, (f4v*)(dp + 4));

    if (sub < 16){
      float accf = b2[sub];
      for (int h2 = 0; h2 < 128; ++h2) accf += sx[ls*128 + h2] * W2[h2*16 + sub];
      __builtin_nontemporal_store(accf, &f_out[bS*16 + sub]);
    }
  }

  // ---- d2f main loop: A-frag on the fly feeds 32 MFMAs (8 samples), cached dwordx4 store ----
  const int R0 = mb*1024 + wave*256;    // each wave: 256 rows = 16 m-tiles
#pragma unroll 2
  for (int mt = 0; mt < 16; ++mt){
    const int rowbase = R0 + mt*16;
    const int r = rowbase + n;          // U row
    const int i = r & 63;
    const int k = r >> 6;               // uniform within the tile
    const float* wi = &sW1[i*W1S];
    const float* wk = &sW1[k*W1S];
    s8v afrag[4];
#pragma unroll
    for (int ks = 0; ks < 4; ++ks){
      int c = q*8 + ks*32;
      f4v ia = *(const f4v*)&wi[c];
      f4v ib = *(const f4v*)&wi[c+4];
      f4v ka = *(const f4v*)&wk[c];
      f4v kb = *(const f4v*)&wk[c+4];
      s8v av;
#pragma unroll
      for (int e = 0; e < 4; ++e) av[e]   = (short)f2bf(ia[e]*ka[e]);
#pragma unroll
      for (int e = 0; e < 4; ++e) av[4+e] = (short)f2bf(ib[e]*kb[e]);
      afrag[ks] = av;
    }
#pragma unroll
    for (int s = 0; s < 8; ++s){
      f4v acc = {0.f, 0.f, 0.f, 0.f};
#pragma unroll
      for (int ks = 0; ks < 4; ++ks)
        acc = __builtin_amdgcn_mfma_f32_16x16x32_bf16(bfrag[s][ks], afrag[ks], acc, 0, 0, 0);
      // D' = (U@G)^T: lane(n,q) holds d2f[b0+s][rowbase+n][q*4 .. q*4+3]
      float* op = d2f + (size_t)(b0 + s)*65536 + (size_t)(rowbase + n)*16 + q*4;
      *(f4v*)op = acc;                  // cached store
    }
  }
}

extern "C" void kernel_launch(void* const* d_in, const int* in_sizes, int n_in,
                              void* d_out, int out_size, void* d_ws, size_t ws_size,
                              hipStream_t stream)
{
  (void)in_sizes; (void)n_in; (void)out_size; (void)d_ws; (void)ws_size;
  const float* x  = (const float*)d_in[0];
  const float* W1 = (const float*)d_in[1];
  const float* b1 = (const float*)d_in[2];
  const float* W2 = (const float*)d_in[3];
  const float* b2 = (const float*)d_in[4];

  float* out     = (float*)d_out;
  float* f_out   = out;                    // 16384
  float* df_out  = out + 16384;            // 1048576
  float* d2f_out = out + 1064960;          // 67108864

  k_all<<<dim3(128, 4), 256, 0, stream>>>(x, W1, b1, W2, b2, f_out, df_out, d2f_out);
}

// Round 6
// 277.541 us; speedup vs baseline: 1.0231x; 1.0231x over previous
//
#include <hip/hip_runtime.h>
#include <hip/hip_bf16.h>

// B=1024, D_IN=64, H=128, D_OUT=16
// inputs:  fp32  x[1024,64] W1[64,128] b1[128] W2[128,16] b2[16]
// outputs: fp32, flat: f[1024*16] | df[1024*64*16] | d2f[1024*64*64*16]
//
// Math per sample: z = x@W1+b1, a=tanh(z), s=1-a^2, t=-2*a*s
//   f          = a@W2 + b2
//   df[i,j]    = sum_h W1[i,h] s_h W2[h,j]          (exact f32)
//   d2f[k,i,j] = sum_h W1[i,h] W1[k,h] t_h W2[h,j]  (bf16 MFMA, f32 acc)
//
// R4 structure (best: 276 us) + SYMMETRY: d2f[k,i,j]==d2f[i,k,j] bit-exactly
// (same bf16 products, same MFMA dot order). Compute only the 4 diagonal +
// 6 upper 16x16 (k,i)-blocks (62.5% of tiles); lower blocks are written as
// mirror stores of the same accumulators. k,k+1 tile-pairs share the i-side
// LDS reads and make mirror stores cover full 128B lines. Store volume
// unchanged (260 MiB); MFMA/LDS/VALU in the main loop x0.56-0.625.

typedef unsigned short u16;
typedef short s8v __attribute__((ext_vector_type(8)));   // 8 bf16 = 4 VGPRs (A/B frag)
typedef float f4v __attribute__((ext_vector_type(4)));

__device__ __forceinline__ u16 f2bf(float f){
  __hip_bfloat16 h = __float2bfloat16(f);   // RNE
  return __builtin_bit_cast(u16, h);
}

#define W1S 132   // padded LDS stride for W1 rows

__global__ __launch_bounds__(256, 2) void k_all(
    const float* __restrict__ x, const float* __restrict__ W1, const float* __restrict__ b1,
    const float* __restrict__ W2, const float* __restrict__ b2,
    float* __restrict__ f_out, float* __restrict__ df_out, float* __restrict__ d2f)
{
  const int tid  = threadIdx.x;
  const int lane = tid & 63;
  const int wave = tid >> 6;
  const int n = lane & 15;      // MFMA position
  const int q = lane >> 4;      // quad (K-block)
  const int b0 = blockIdx.x * 4;
  const int mb = blockIdx.y;    // 0/1: tile-half AND f/df sample-pair selector

  __shared__ float sW1[64 * W1S];            // f32 W1, padded rows (33.8 KB)
  __shared__ __align__(16) float sGF[4096];  // phase A: bf16 G swizzled; phase B: f32 s*W2 (16 KB)
  __shared__ float sx[256];                  // phase A: x for 4 samples; phase B: a for 2 samples
  u16* sG = (u16*)sGF;

  // ---- stage W1 (8192 floats) and x ----
#pragma unroll
  for (int v = 0; v < 8; ++v){
    int idx = v*256 + tid;              // float4 index
    int r = idx >> 5;
    int c = (idx & 31) << 2;
    *(f4v*)&sW1[r*W1S + c] = *(const f4v*)&W1[r*128 + c];
  }
  sx[tid] = x[b0*64 + tid];
  __syncthreads();

  // ---- z-pass: all 4 samples -> sG (bf16, XOR-swizzled). Keep a,s of it==mb in regs ----
  float a_keep = 0.f, s_keep = 0.f;
#pragma unroll
  for (int it = 0; it < 2; ++it){
    int idx = it*256 + tid;             // (s,h) item
    int s = idx >> 7;                   // = it*2 + (tid>>7)
    int h = idx & 127;
    float z = b1[h];
#pragma unroll 8
    for (int i = 0; i < 64; ++i) z += sx[s*64 + i] * sW1[i*W1S + h];
    float a = tanhf(z);
    float sd = 1.0f - a*a;              // tanh'
    float t = -2.0f * a * sd;           // tanh''
    if (it == mb){ a_keep = a; s_keep = sd; }
    f4v w2r[4];
#pragma unroll
    for (int v2 = 0; v2 < 4; ++v2) w2r[v2] = *(const f4v*)&W2[h*16 + v2*4];
#pragma unroll
    for (int j = 0; j < 16; ++j){
      int byte = (j*256 + h*2) ^ ((j & 7) << 4);   // bank-spread swizzle
      sG[s*2048 + (byte >> 1)] = f2bf(t * w2r[j >> 2][j & 3]);
    }
  }
  __syncthreads();

  // ---- B-fragments (G^T): lane(n,q), ks -> G[s][j=n][h=q*8+ks*32+e] ----
  s8v bfrag[4][4];
#pragma unroll
  for (int s = 0; s < 4; ++s){
#pragma unroll
    for (int ks = 0; ks < 4; ++ks){
      int byte = (n*256 + q*16 + ks*64) ^ ((n & 7) << 4);
      bfrag[s][ks] = *(const s8v*)&sG[s*2048 + (byte >> 1)];
    }
  }
  __syncthreads();   // all sG reads complete -> safe to repurpose sGF/sx

  // ---- phase B: f and df for samples {b0+2mb, b0+2mb+1} (exact f32, mirrors old k1) ----
  {
    const int ls = tid >> 7;            // 0/1 = local sample
    const int h  = tid & 127;
    float* sF = sGF;                    // [2][128][16] f32 s*W2
    sx[tid] = a_keep;                   // sx[ls*128+h] == a of sample b0+2mb+ls
    f4v w2r[4];
#pragma unroll
    for (int v2 = 0; v2 < 4; ++v2) w2r[v2] = *(const f4v*)&W2[h*16 + v2*4];
#pragma unroll
    for (int v2 = 0; v2 < 4; ++v2){
      f4v sv;
#pragma unroll
      for (int e = 0; e < 4; ++e) sv[e] = s_keep * w2r[v2][e];
      *(f4v*)&sF[ls*2048 + h*16 + v2*4] = sv;
    }
    __syncthreads();

    const int sub = tid & 127;
    const int i   = sub >> 1;
    const int j0  = (sub & 1) * 8;
    const int bS  = b0 + 2*mb + ls;
    float acc[8] = {0,0,0,0,0,0,0,0};
    for (int h0 = 0; h0 < 128; h0 += 8){
      const float4* wp = (const float4*)&W1[i*128 + h0];   // global, L1-hot, exact k1 order
      float4 wa = wp[0], wb = wp[1];
      float wf[8] = {wa.x, wa.y, wa.z, wa.w, wb.x, wb.y, wb.z, wb.w};
#pragma unroll
      for (int hh = 0; hh < 8; ++hh){
        const f4v* sp = (const f4v*)&sF[ls*2048 + (h0 + hh)*16 + j0];
        f4v A = sp[0], Bv = sp[1];
        float w1 = wf[hh];
        acc[0] += w1*A[0];  acc[1] += w1*A[1];  acc[2] += w1*A[2];  acc[3] += w1*A[3];
        acc[4] += w1*Bv[0]; acc[5] += w1*Bv[1]; acc[6] += w1*Bv[2]; acc[7] += w1*Bv[3];
      }
    }
    f4v v0 = {acc[0], acc[1], acc[2], acc[3]};
    f4v v1 = {acc[4], acc[5], acc[6], acc[7]};
    float* dp = &df_out[bS*1024 + i*16 + j0];
    __builtin_nontemporal_store(v0, (f4v*)dp);
    __builtin_nontemporal_store(v1, (f4v*)(dp + 4));

    if (sub < 16){
      float accf = b2[sub];
      for (int h2 = 0; h2 < 128; ++h2) accf += sx[ls*128 + h2] * W2[h2*16 + sub];
      __builtin_nontemporal_store(accf, &f_out[bS*16 + sub]);
    }
  }

  // ---- d2f main loop: symmetric tile-pairs, mirror stores for off-diagonal blocks ----
  // (k,i) space = 4x4 blocks of 16x16. Block order: 0-3 diag (KB=IB=blk),
  // 4-9 upper: (0,1)(0,2)(0,3)(1,2)(1,3)(2,3). 80 k-pairs total, 10 per wave.
  // KB nibbles {0,1,2,3,0,0,0,1,1,2} ; IB nibbles {0,1,2,3,1,2,3,2,3,3}.
  const int w8 = mb*4 + wave;       // 0..7
  const size_t sB0 = (size_t)b0 * 65536;
#pragma unroll 2
  for (int pp = 0; pp < 10; ++pp){
    const int p   = w8*10 + pp;     // global pair id 0..79
    const int blk = p >> 3;         // 0..9 (8 pairs per block)
    const int kk2 = (p & 7) * 2;
    const int KB  = (int)((0x2110003210ULL >> (4*blk)) & 15);
    const int IB  = (int)((0x3323213210ULL >> (4*blk)) & 15);
    const int k   = KB*16 + kk2;    // even; pair is (k, k+1)
    const int I0  = IB*16;
    const bool diag = (blk < 4);

    const int i = I0 + n;           // lane's i-row (shared by both tiles of the pair)
    const float* wi  = &sW1[i*W1S];
    const float* wkA = &sW1[k*W1S];
    const float* wkB = &sW1[(k+1)*W1S];
    s8v afK[4], afK1[4];
#pragma unroll
    for (int ks = 0; ks < 4; ++ks){
      int c = q*8 + ks*32;
      f4v ia = *(const f4v*)&wi[c];
      f4v ib = *(const f4v*)&wi[c+4];
      f4v ka = *(const f4v*)&wkA[c];
      f4v kb = *(const f4v*)&wkA[c+4];
      f4v kc = *(const f4v*)&wkB[c];
      f4v kd = *(const f4v*)&wkB[c+4];
      s8v a0, a1;
#pragma unroll
      for (int e = 0; e < 4; ++e){
        a0[e]   = (short)f2bf(ia[e]*ka[e]);
        a0[4+e] = (short)f2bf(ib[e]*kb[e]);
        a1[e]   = (short)f2bf(ia[e]*kc[e]);
        a1[4+e] = (short)f2bf(ib[e]*kd[e]);
      }
      afK[ks] = a0; afK1[ks] = a1;
    }
#pragma unroll
    for (int s = 0; s < 4; ++s){
      f4v accK = {0.f,0.f,0.f,0.f}, accK1 = {0.f,0.f,0.f,0.f};
#pragma unroll
      for (int ks = 0; ks < 4; ++ks){
        accK  = __builtin_amdgcn_mfma_f32_16x16x32_bf16(bfrag[s][ks], afK[ks],  accK,  0, 0, 0);
        accK1 = __builtin_amdgcn_mfma_f32_16x16x32_bf16(bfrag[s][ks], afK1[ks], accK1, 0, 0, 0);
      }
      float* baseS = d2f + sB0 + (size_t)s*65536;
      // normal (contiguous 1KB/wave) stores: row r = k*64 + i
      *(f4v*)(baseS + (size_t)(k*64 + i)*16 + q*4)       = accK;
      *(f4v*)(baseS + (size_t)((k+1)*64 + i)*16 + q*4)   = accK1;
      if (!diag){
        // mirror: row r' = i*64 + k (+1 for K1). k even -> the two 64B halves
        // from accK/accK1 complete each 128B line. Bit-identical values.
        float* mp = baseS + (size_t)(i*64 + k)*16 + q*4;
        *(f4v*)mp        = accK;
        *(f4v*)(mp + 16) = accK1;
      }
    }
  }
}

extern "C" void kernel_launch(void* const* d_in, const int* in_sizes, int n_in,
                              void* d_out, int out_size, void* d_ws, size_t ws_size,
                              hipStream_t stream)
{
  (void)in_sizes; (void)n_in; (void)out_size; (void)d_ws; (void)ws_size;
  const float* x  = (const float*)d_in[0];
  const float* W1 = (const float*)d_in[1];
  const float* b1 = (const float*)d_in[2];
  const float* W2 = (const float*)d_in[3];
  const float* b2 = (const float*)d_in[4];

  float* out     = (float*)d_out;
  float* f_out   = out;                    // 16384
  float* df_out  = out + 16384;            // 1048576
  float* d2f_out = out + 1064960;          // 67108864

  k_all<<<dim3(256, 2), 256, 0, stream>>>(x, W1, b1, W2, b2, f_out, df_out, d2f_out);
}